// Round 3
// baseline (1442.138 us; speedup 1.0000x reference)
//
#include <hip/hip_runtime.h>
#include <math.h>
#include <stdint.h>

#define NN 100000
#define NE 1600000
#define IN_DIM 128
#define HID 64
#define EDIM 16
#define NEG_SLOPE 0.2f

// ws layout (float offsets)
#define OFF_H    0          // NN*4
#define OFF_HS   400000     // NN
#define OFF_HD   500000     // NN
#define OFF_DEN  600000     // NN
#define OFF_XG   700000     // NN*4
#define OFF_P    1100000    // NE+NN  (ends at 2800000)
#define OFF_IMG  2800000    // 19*256 u32 = 4864

typedef __attribute__((ext_vector_type(8))) short bf16x8;
typedef __attribute__((ext_vector_type(4))) float f32x4;

#define MFMA16(A, B, C) __builtin_amdgcn_mfma_f32_16x16x32_bf16((A), (B), (C), 0, 0, 0)

__device__ inline uint32_t cvtpk(float lo, float hi) {
    uint32_t r;
    asm("v_cvt_pk_bf16_f32 %0, %1, %2" : "=v"(r) : "v"(lo), "v"(hi));
    return r;
}
// v_permlane16_swap_b32 a, b: a'[row1]=b[row0], a'[row3]=b[row2], b'[row0]=a[row1], b'[row2]=a[row3]
// (rows = 16-lane groups). With a==b==x: a'=[x0,x0,x2,x2], b'=[x1,x1,x3,x3].
__device__ inline void pl16(uint32_t& a, uint32_t& b) {
    asm("v_permlane16_swap_b32 %0, %1" : "+v"(a), "+v"(b));
}
// v_permlane32_swap_b32 a, b: a' = [a.lo32, b.lo32], b' = [a.hi32, b.hi32] (g-rows: a'=[a0,a1,b0,b1])
__device__ inline void pl32(uint32_t& a, uint32_t& b) {
    asm("v_permlane32_swap_b32 %0, %1" : "+v"(a), "+v"(b));
}
__device__ inline bf16x8 as_bf(uint4 x) { union { uint4 a; bf16x8 b; } u; u.a = x; return u.b; }

// ---------------- GAT conv (unchanged, passed r1/r2) ----------------
__global__ void node_kernel(const float* __restrict__ x, const float* __restrict__ Wg,
                            const float* __restrict__ a_src, const float* __restrict__ a_dst,
                            const float* __restrict__ b_gat,
                            float* __restrict__ h, float* __restrict__ hs,
                            float* __restrict__ hd, float* __restrict__ den,
                            float* __restrict__ xg) {
    int i = blockIdx.x * blockDim.x + threadIdx.x;
    if (i >= NN) return;
    float acc0 = 0.f, acc1 = 0.f, acc2 = 0.f, acc3 = 0.f;
    const float* xr = x + (size_t)i * IN_DIM;
#pragma unroll
    for (int d = 0; d < IN_DIM; d += 4) {
        float4 xv = *(const float4*)(xr + d);
        acc0 = fmaf(xv.x, Wg[(d + 0) * 4 + 0], acc0);
        acc1 = fmaf(xv.x, Wg[(d + 0) * 4 + 1], acc1);
        acc2 = fmaf(xv.x, Wg[(d + 0) * 4 + 2], acc2);
        acc3 = fmaf(xv.x, Wg[(d + 0) * 4 + 3], acc3);
        acc0 = fmaf(xv.y, Wg[(d + 1) * 4 + 0], acc0);
        acc1 = fmaf(xv.y, Wg[(d + 1) * 4 + 1], acc1);
        acc2 = fmaf(xv.y, Wg[(d + 1) * 4 + 2], acc2);
        acc3 = fmaf(xv.y, Wg[(d + 1) * 4 + 3], acc3);
        acc0 = fmaf(xv.z, Wg[(d + 2) * 4 + 0], acc0);
        acc1 = fmaf(xv.z, Wg[(d + 2) * 4 + 1], acc1);
        acc2 = fmaf(xv.z, Wg[(d + 2) * 4 + 2], acc2);
        acc3 = fmaf(xv.z, Wg[(d + 2) * 4 + 3], acc3);
        acc0 = fmaf(xv.w, Wg[(d + 3) * 4 + 0], acc0);
        acc1 = fmaf(xv.w, Wg[(d + 3) * 4 + 1], acc1);
        acc2 = fmaf(xv.w, Wg[(d + 3) * 4 + 2], acc2);
        acc3 = fmaf(xv.w, Wg[(d + 3) * 4 + 3], acc3);
    }
    *(float4*)(h + (size_t)i * 4) = make_float4(acc0, acc1, acc2, acc3);
    hs[i] = acc0 * a_src[0] + acc1 * a_src[1] + acc2 * a_src[2] + acc3 * a_src[3];
    hd[i] = acc0 * a_dst[0] + acc1 * a_dst[1] + acc2 * a_dst[2] + acc3 * a_dst[3];
    den[i] = 0.f;
    *(float4*)(xg + (size_t)i * 4) = make_float4(b_gat[0], b_gat[1], b_gat[2], b_gat[3]);
}

__global__ void att_kernel(const int* __restrict__ ei, const float* __restrict__ hs,
                           const float* __restrict__ hd, float* __restrict__ p,
                           float* __restrict__ den) {
    int e = blockIdx.x * blockDim.x + threadIdx.x;
    if (e >= NE + NN) return;
    int r, c;
    if (e < NE) { r = ei[e]; c = ei[NE + e]; }
    else { r = e - NE; c = r; }
    float v = hs[r] + hd[c];
    v = (v >= 0.f) ? v : NEG_SLOPE * v;
    float pe = expf(v);
    p[e] = pe;
    atomicAdd(&den[c], pe);
}

__global__ void agg_kernel(const int* __restrict__ ei, const float* __restrict__ h,
                           const float* __restrict__ p, const float* __restrict__ den,
                           float* __restrict__ xg) {
    int e = blockIdx.x * blockDim.x + threadIdx.x;
    if (e >= NE + NN) return;
    int r, c;
    if (e < NE) { r = ei[e]; c = ei[NE + e]; }
    else { r = e - NE; c = r; }
    float alpha = p[e] / den[c];
    float4 hv = *(const float4*)(h + (size_t)r * 4);
    atomicAdd(&xg[4 * c + 0], hv.x * alpha);
    atomicAdd(&xg[4 * c + 1], hv.y * alpha);
    atomicAdd(&xg[4 * c + 2], hv.z * alpha);
    atomicAdd(&xg[4 * c + 3], hv.w * alpha);
}

// ---------------- fragment image prep (unchanged, validated r2) ----------------
__device__ inline uint16_t f2bf_rne(float f) {
    uint32_t x = __float_as_uint(f);
    uint32_t r = x + 0x7FFFu + ((x >> 16) & 1u);
    return (uint16_t)(r >> 16);
}
__device__ inline uint32_t pk2(float lo, float hi) {
    return (uint32_t)f2bf_rne(lo) | ((uint32_t)f2bf_rne(hi) << 16);
}

__global__ void prep_kernel(const float* __restrict__ W1, const float* __restrict__ b1,
                            const float* __restrict__ W2, const float* __restrict__ b2,
                            const float* __restrict__ W3, const float* __restrict__ b3,
                            uint32_t* __restrict__ img) {
    int l = threadIdx.x;
    if (l >= 64) return;
    int e = l & 15, g = l >> 4;
    for (int q = 0; q < 4; ++q) {
        int m = 16 * q + e;
        for (int j2 = 0; j2 < 4; ++j2) {
            int k0 = 8 * g + 2 * j2, k1 = k0 + 1;
            float a = (k0 < 24) ? W1[k0 * 64 + m] : (k0 == 24 ? b1[m] : 0.f);
            float b = (k1 < 24) ? W1[k1 * 64 + m] : (k1 == 24 ? b1[m] : 0.f);
            img[q * 256 + l * 4 + j2] = pk2(a, b);
        }
    }
    for (int t = 0; t < 2; ++t)
        for (int q = 0; q < 4; ++q) {
            int m = 16 * q + e;
            for (int j2 = 0; j2 < 4; ++j2) {
                int k0 = 32 * t + 8 * g + 2 * j2;
                img[(4 + t * 4 + q) * 256 + l * 4 + j2] =
                    pk2(W2[k0 * 64 + m], W2[(k0 + 1) * 64 + m]);
            }
        }
    for (int t = 0; t < 2; ++t)
        for (int j2 = 0; j2 < 4; ++j2) {
            int k0 = 32 * t + 8 * g + 2 * j2;
            img[(12 + t) * 256 + l * 4 + j2] =
                pk2(W3[k0 * 16 + e], W3[(k0 + 1) * 16 + e]);
        }
    for (int q = 0; q < 4; ++q)
        for (int r = 0; r < 4; ++r)
            img[(14 + q) * 256 + l * 4 + r] = __float_as_uint(b2[16 * q + 4 * g + r]);
    for (int r = 0; r < 4; ++r)
        img[18 * 256 + l * 4 + r] = __float_as_uint(b3[4 * g + r]);
}

// ---------------- RK4 edge MLP: MFMA + permlane, ZERO LDS ----------------
// Wave = 16 edges. C/D layout: col=lane&15 (edge), row=4*(lane>>4)+reg (feat).
// B layout: col=lane&15, k = 8*(lane>>4)+j contiguous.
// Inter-layer feat->k transform done with v_permlane{16,32}_swap_b32 (VALU only).
__global__ __launch_bounds__(256) void rk4_kernel(
    const int* __restrict__ ei, const float* __restrict__ ea,
    const float* __restrict__ xg, const uint32_t* __restrict__ img,
    float* __restrict__ out) {
    const int tid = threadIdx.x;
    const int w = tid >> 6, l = tid & 63;
    const int e = l & 15, g = l >> 4;
    const int edge = blockIdx.x * 64 + w * 16 + e;

    // persistent weight fragments
    bf16x8 W1f[4], W2f[2][4], W3f[2];
    f32x4 b2f[4], b3f;
    {
        union { uint4 a; bf16x8 b; f32x4 f; } t;
#pragma unroll
        for (int q = 0; q < 4; ++q) { t.a = *(const uint4*)(img + q * 256 + l * 4); W1f[q] = t.b; }
#pragma unroll
        for (int tt = 0; tt < 2; ++tt)
#pragma unroll
            for (int q = 0; q < 4; ++q) {
                t.a = *(const uint4*)(img + (4 + tt * 4 + q) * 256 + l * 4);
                W2f[tt][q] = t.b;
            }
#pragma unroll
        for (int tt = 0; tt < 2; ++tt) { t.a = *(const uint4*)(img + (12 + tt) * 256 + l * 4); W3f[tt] = t.b; }
#pragma unroll
        for (int q = 0; q < 4; ++q) { t.a = *(const uint4*)(img + (14 + q) * 256 + l * 4); b2f[q] = t.f; }
        t.a = *(const uint4*)(img + 18 * 256 + l * 4); b3f = t.f;
    }

    // per-lane static rows of layer-1 B operand:
    //   row g0: f = [src0..3, tgt0..3] packed; row g3: k=24 is bias-one (bf16 1.0)
    uint32_t St0 = 0u, St1 = 0u, St2 = 0u, St3 = 0u;
    if (g == 0) {
        int r = ei[edge], c = ei[NE + edge];
        float4 sv = *(const float4*)(xg + (size_t)r * 4);
        float4 tv = *(const float4*)(xg + (size_t)c * 4);
        St0 = cvtpk(sv.x, sv.y); St1 = cvtpk(sv.z, sv.w);
        St2 = cvtpk(tv.x, tv.y); St3 = cvtpk(tv.z, tv.w);
    } else if (g == 3) {
        St0 = 0x00003F80u;  // bf16(1.0) at k=24
    }
    const bool mid = (g == 1) || (g == 2);

    float4 y4 = *(const float4*)(ea + (size_t)edge * 16 + 4 * g);
    float yv0 = y4.x, yv1 = y4.y, yv2 = y4.z, yv3 = y4.w;

    const f32x4 zero4 = {0.f, 0.f, 0.f, 0.f};
    const float dt6 = 0.125f / 6.0f;

    // rhs(a0..a3) -> kk (lane holds feats 4g..4g+3 of its edge)
    auto rhs = [&](float a0, float a1, float a2, float a3) -> f32x4 {
        // ---- build layer-1 B: rows g1/g2 from arg via permlane, g0/g3 static ----
        uint32_t aP = cvtpk(a0, a1), bP = cvtpk(a2, a3);
        uint32_t A1 = aP, A2 = aP; pl16(A1, A2);   // A1=[a0,a0,a2,a2] A2=[a1,a1,a3,a3] (g-rows)
        uint32_t C1 = bP, C2 = bP; pl16(C1, C2);
        uint4 bb;
        bb.x = mid ? A1 : St0;
        bb.y = mid ? C1 : St1;
        bb.z = mid ? A2 : St2;
        bb.w = mid ? C2 : St3;
        bf16x8 B1 = as_bf(bb);
        // ---- layer 1 (K=32, bias folded at k=24) ----
        f32x4 h0 = MFMA16(W1f[0], B1, zero4);
        f32x4 h1 = MFMA16(W1f[1], B1, zero4);
        f32x4 h2 = MFMA16(W1f[2], B1, zero4);
        f32x4 h3 = MFMA16(W1f[3], B1, zero4);
        // ---- relu + pack + transpose to B20/B21 ----
        uint32_t x0 = cvtpk(fmaxf(h0[0], 0.f), fmaxf(h0[1], 0.f));
        uint32_t x1 = cvtpk(fmaxf(h0[2], 0.f), fmaxf(h0[3], 0.f));
        uint32_t u0 = cvtpk(fmaxf(h1[0], 0.f), fmaxf(h1[1], 0.f));
        uint32_t u1 = cvtpk(fmaxf(h1[2], 0.f), fmaxf(h1[3], 0.f));
        uint32_t z0 = cvtpk(fmaxf(h2[0], 0.f), fmaxf(h2[1], 0.f));
        uint32_t z1 = cvtpk(fmaxf(h2[2], 0.f), fmaxf(h2[3], 0.f));
        uint32_t v0 = cvtpk(fmaxf(h3[0], 0.f), fmaxf(h3[1], 0.f));
        uint32_t v1 = cvtpk(fmaxf(h3[2], 0.f), fmaxf(h3[3], 0.f));
        pl32(x0, u0); pl16(x0, u0);   // x0=j0, u0=j2 of B20
        pl32(x1, u1); pl16(x1, u1);   // x1=j1, u1=j3
        pl32(z0, v0); pl16(z0, v0);   // B21
        pl32(z1, v1); pl16(z1, v1);
        uint4 q20; q20.x = x0; q20.y = x1; q20.z = u0; q20.w = u1;
        uint4 q21; q21.x = z0; q21.y = z1; q21.z = v0; q21.w = v1;
        bf16x8 B20 = as_bf(q20), B21 = as_bf(q21);
        // ---- layer 2 (K=64, bias via C-in) ----
        f32x4 p0 = MFMA16(W2f[0][0], B20, b2f[0]); p0 = MFMA16(W2f[1][0], B21, p0);
        f32x4 p1 = MFMA16(W2f[0][1], B20, b2f[1]); p1 = MFMA16(W2f[1][1], B21, p1);
        f32x4 p2 = MFMA16(W2f[0][2], B20, b2f[2]); p2 = MFMA16(W2f[1][2], B21, p2);
        f32x4 p3 = MFMA16(W2f[0][3], B20, b2f[3]); p3 = MFMA16(W2f[1][3], B21, p3);
        // ---- relu + pack + transpose to B30/B31 ----
        uint32_t m0 = cvtpk(fmaxf(p0[0], 0.f), fmaxf(p0[1], 0.f));
        uint32_t m1 = cvtpk(fmaxf(p0[2], 0.f), fmaxf(p0[3], 0.f));
        uint32_t n0 = cvtpk(fmaxf(p1[0], 0.f), fmaxf(p1[1], 0.f));
        uint32_t n1 = cvtpk(fmaxf(p1[2], 0.f), fmaxf(p1[3], 0.f));
        uint32_t o0 = cvtpk(fmaxf(p2[0], 0.f), fmaxf(p2[1], 0.f));
        uint32_t o1 = cvtpk(fmaxf(p2[2], 0.f), fmaxf(p2[3], 0.f));
        uint32_t r0 = cvtpk(fmaxf(p3[0], 0.f), fmaxf(p3[1], 0.f));
        uint32_t r1 = cvtpk(fmaxf(p3[2], 0.f), fmaxf(p3[3], 0.f));
        pl32(m0, n0); pl16(m0, n0);
        pl32(m1, n1); pl16(m1, n1);
        pl32(o0, r0); pl16(o0, r0);
        pl32(o1, r1); pl16(o1, r1);
        uint4 q30; q30.x = m0; q30.y = m1; q30.z = n0; q30.w = n1;
        uint4 q31; q31.x = o0; q31.y = o1; q31.z = r0; q31.w = r1;
        bf16x8 B30 = as_bf(q30), B31 = as_bf(q31);
        // ---- layer 3 (K=64, M=16) ----
        f32x4 kk = MFMA16(W3f[0], B30, b3f);
        kk = MFMA16(W3f[1], B31, kk);
        return kk;
    };

#pragma unroll 1
    for (int step = 0; step < 8; ++step) {
        f32x4 k1 = rhs(yv0, yv1, yv2, yv3);
        f32x4 k2 = rhs(fmaf(0.0625f, k1[0], yv0), fmaf(0.0625f, k1[1], yv1),
                       fmaf(0.0625f, k1[2], yv2), fmaf(0.0625f, k1[3], yv3));
        f32x4 k3 = rhs(fmaf(0.0625f, k2[0], yv0), fmaf(0.0625f, k2[1], yv1),
                       fmaf(0.0625f, k2[2], yv2), fmaf(0.0625f, k2[3], yv3));
        f32x4 k4 = rhs(fmaf(0.125f, k3[0], yv0), fmaf(0.125f, k3[1], yv1),
                       fmaf(0.125f, k3[2], yv2), fmaf(0.125f, k3[3], yv3));
        yv0 = fmaf(dt6, k1[0] + 2.f * k2[0] + 2.f * k3[0] + k4[0], yv0);
        yv1 = fmaf(dt6, k1[1] + 2.f * k2[1] + 2.f * k3[1] + k4[1], yv1);
        yv2 = fmaf(dt6, k1[2] + 2.f * k2[2] + 2.f * k3[2] + k4[2], yv2);
        yv3 = fmaf(dt6, k1[3] + 2.f * k2[3] + 2.f * k3[3] + k4[3], yv3);
    }

    *(float4*)(out + (size_t)edge * 16 + 4 * g) = make_float4(yv0, yv1, yv2, yv3);
}

extern "C" void kernel_launch(void* const* d_in, const int* in_sizes, int n_in,
                              void* d_out, int out_size, void* d_ws, size_t ws_size,
                              hipStream_t stream) {
    const float* x     = (const float*)d_in[0];
    const int*   ei    = (const int*)d_in[1];
    const float* ea    = (const float*)d_in[2];
    const float* Wg    = (const float*)d_in[3];
    const float* a_src = (const float*)d_in[4];
    const float* a_dst = (const float*)d_in[5];
    const float* b_gat = (const float*)d_in[6];
    const float* W1    = (const float*)d_in[7];
    const float* b1    = (const float*)d_in[8];
    const float* W2    = (const float*)d_in[9];
    const float* b2    = (const float*)d_in[10];
    const float* W3    = (const float*)d_in[11];
    const float* b3    = (const float*)d_in[12];

    float* ws  = (float*)d_ws;
    float* h   = ws + OFF_H;
    float* hs  = ws + OFF_HS;
    float* hd  = ws + OFF_HD;
    float* den = ws + OFF_DEN;
    float* xg  = ws + OFF_XG;
    float* p   = ws + OFF_P;
    uint32_t* img = (uint32_t*)(ws + OFF_IMG);

    prep_kernel<<<1, 64, 0, stream>>>(W1, b1, W2, b2, W3, b3, img);
    node_kernel<<<(NN + 255) / 256, 256, 0, stream>>>(x, Wg, a_src, a_dst, b_gat,
                                                      h, hs, hd, den, xg);
    int ne_tot = NE + NN;
    att_kernel<<<(ne_tot + 255) / 256, 256, 0, stream>>>(ei, hs, hd, p, den);
    agg_kernel<<<(ne_tot + 255) / 256, 256, 0, stream>>>(ei, h, p, den, xg);
    rk4_kernel<<<NE / 64, 256, 0, stream>>>(ei, ea, xg, img, (float*)d_out);
}

// Round 4
// 1317.731 us; speedup vs baseline: 1.0944x; 1.0944x over previous
//
#include <hip/hip_runtime.h>
#include <math.h>
#include <stdint.h>

#define NN 100000
#define NE 1600000
#define IN_DIM 128
#define HID 64
#define EDIM 16
#define NEG_SLOPE 0.2f

// ws layout (float offsets)
#define OFF_H    0          // NN*4
#define OFF_HS   400000     // NN
#define OFF_HD   500000     // NN
#define OFF_DEN  600000     // NN
#define OFF_XG   700000     // NN*4
#define OFF_P    1100000    // NE+NN  (ends at 2800000)
#define OFF_IMG  2800000    // 19*256 u32 = 4864

typedef __attribute__((ext_vector_type(8))) short bf16x8;
typedef __attribute__((ext_vector_type(4))) float f32x4;

#define MFMA16(A, B, C) __builtin_amdgcn_mfma_f32_16x16x32_bf16((A), (B), (C), 0, 0, 0)

__device__ inline uint32_t cvtpk(float lo, float hi) {
    uint32_t r;
    asm("v_cvt_pk_bf16_f32 %0, %1, %2" : "=v"(r) : "v"(lo), "v"(hi));
    return r;
}
// v_permlane16_swap_b32 a, b: swaps odd 16-rows of a with even 16-rows of b.
// With a==b==x: a'=[x0,x0,x2,x2], b'=[x1,x1,x3,x3] (g-rows).
__device__ inline void pl16(uint32_t& a, uint32_t& b) {
    asm("v_permlane16_swap_b32 %0, %1" : "+v"(a), "+v"(b));
}
// v_permlane32_swap_b32 a, b: a' = [a.lo32, b.lo32], b' = [a.hi32, b.hi32]
__device__ inline void pl32(uint32_t& a, uint32_t& b) {
    asm("v_permlane32_swap_b32 %0, %1" : "+v"(a), "+v"(b));
}
__device__ inline bf16x8 as_bf(uint4 x) { union { uint4 a; bf16x8 b; } u; u.a = x; return u.b; }

// ---------------- GAT conv (unchanged, passed r1-r3) ----------------
__global__ void node_kernel(const float* __restrict__ x, const float* __restrict__ Wg,
                            const float* __restrict__ a_src, const float* __restrict__ a_dst,
                            const float* __restrict__ b_gat,
                            float* __restrict__ h, float* __restrict__ hs,
                            float* __restrict__ hd, float* __restrict__ den,
                            float* __restrict__ xg) {
    int i = blockIdx.x * blockDim.x + threadIdx.x;
    if (i >= NN) return;
    float acc0 = 0.f, acc1 = 0.f, acc2 = 0.f, acc3 = 0.f;
    const float* xr = x + (size_t)i * IN_DIM;
#pragma unroll
    for (int d = 0; d < IN_DIM; d += 4) {
        float4 xv = *(const float4*)(xr + d);
        acc0 = fmaf(xv.x, Wg[(d + 0) * 4 + 0], acc0);
        acc1 = fmaf(xv.x, Wg[(d + 0) * 4 + 1], acc1);
        acc2 = fmaf(xv.x, Wg[(d + 0) * 4 + 2], acc2);
        acc3 = fmaf(xv.x, Wg[(d + 0) * 4 + 3], acc3);
        acc0 = fmaf(xv.y, Wg[(d + 1) * 4 + 0], acc0);
        acc1 = fmaf(xv.y, Wg[(d + 1) * 4 + 1], acc1);
        acc2 = fmaf(xv.y, Wg[(d + 1) * 4 + 2], acc2);
        acc3 = fmaf(xv.y, Wg[(d + 1) * 4 + 3], acc3);
        acc0 = fmaf(xv.z, Wg[(d + 2) * 4 + 0], acc0);
        acc1 = fmaf(xv.z, Wg[(d + 2) * 4 + 1], acc1);
        acc2 = fmaf(xv.z, Wg[(d + 2) * 4 + 2], acc2);
        acc3 = fmaf(xv.z, Wg[(d + 2) * 4 + 3], acc3);
        acc0 = fmaf(xv.w, Wg[(d + 3) * 4 + 0], acc0);
        acc1 = fmaf(xv.w, Wg[(d + 3) * 4 + 1], acc1);
        acc2 = fmaf(xv.w, Wg[(d + 3) * 4 + 2], acc2);
        acc3 = fmaf(xv.w, Wg[(d + 3) * 4 + 3], acc3);
    }
    *(float4*)(h + (size_t)i * 4) = make_float4(acc0, acc1, acc2, acc3);
    hs[i] = acc0 * a_src[0] + acc1 * a_src[1] + acc2 * a_src[2] + acc3 * a_src[3];
    hd[i] = acc0 * a_dst[0] + acc1 * a_dst[1] + acc2 * a_dst[2] + acc3 * a_dst[3];
    den[i] = 0.f;
    *(float4*)(xg + (size_t)i * 4) = make_float4(b_gat[0], b_gat[1], b_gat[2], b_gat[3]);
}

__global__ void att_kernel(const int* __restrict__ ei, const float* __restrict__ hs,
                           const float* __restrict__ hd, float* __restrict__ p,
                           float* __restrict__ den) {
    int e = blockIdx.x * blockDim.x + threadIdx.x;
    if (e >= NE + NN) return;
    int r, c;
    if (e < NE) { r = ei[e]; c = ei[NE + e]; }
    else { r = e - NE; c = r; }
    float v = hs[r] + hd[c];
    v = (v >= 0.f) ? v : NEG_SLOPE * v;
    float pe = expf(v);
    p[e] = pe;
    atomicAdd(&den[c], pe);
}

__global__ void agg_kernel(const int* __restrict__ ei, const float* __restrict__ h,
                           const float* __restrict__ p, const float* __restrict__ den,
                           float* __restrict__ xg) {
    int e = blockIdx.x * blockDim.x + threadIdx.x;
    if (e >= NE + NN) return;
    int r, c;
    if (e < NE) { r = ei[e]; c = ei[NE + e]; }
    else { r = e - NE; c = r; }
    float alpha = p[e] / den[c];
    float4 hv = *(const float4*)(h + (size_t)r * 4);
    atomicAdd(&xg[4 * c + 0], hv.x * alpha);
    atomicAdd(&xg[4 * c + 1], hv.y * alpha);
    atomicAdd(&xg[4 * c + 2], hv.z * alpha);
    atomicAdd(&xg[4 * c + 3], hv.w * alpha);
}

// ---------------- fragment image prep (unchanged, validated r2/r3) ----------------
__device__ inline uint16_t f2bf_rne(float f) {
    uint32_t x = __float_as_uint(f);
    uint32_t r = x + 0x7FFFu + ((x >> 16) & 1u);
    return (uint16_t)(r >> 16);
}
__device__ inline uint32_t pk2(float lo, float hi) {
    return (uint32_t)f2bf_rne(lo) | ((uint32_t)f2bf_rne(hi) << 16);
}

__global__ void prep_kernel(const float* __restrict__ W1, const float* __restrict__ b1,
                            const float* __restrict__ W2, const float* __restrict__ b2,
                            const float* __restrict__ W3, const float* __restrict__ b3,
                            uint32_t* __restrict__ img) {
    int l = threadIdx.x;
    if (l >= 64) return;
    int e = l & 15, g = l >> 4;
    for (int q = 0; q < 4; ++q) {
        int m = 16 * q + e;
        for (int j2 = 0; j2 < 4; ++j2) {
            int k0 = 8 * g + 2 * j2, k1 = k0 + 1;
            float a = (k0 < 24) ? W1[k0 * 64 + m] : (k0 == 24 ? b1[m] : 0.f);
            float b = (k1 < 24) ? W1[k1 * 64 + m] : (k1 == 24 ? b1[m] : 0.f);
            img[q * 256 + l * 4 + j2] = pk2(a, b);
        }
    }
    for (int t = 0; t < 2; ++t)
        for (int q = 0; q < 4; ++q) {
            int m = 16 * q + e;
            for (int j2 = 0; j2 < 4; ++j2) {
                int k0 = 32 * t + 8 * g + 2 * j2;
                img[(4 + t * 4 + q) * 256 + l * 4 + j2] =
                    pk2(W2[k0 * 64 + m], W2[(k0 + 1) * 64 + m]);
            }
        }
    for (int t = 0; t < 2; ++t)
        for (int j2 = 0; j2 < 4; ++j2) {
            int k0 = 32 * t + 8 * g + 2 * j2;
            img[(12 + t) * 256 + l * 4 + j2] =
                pk2(W3[k0 * 16 + e], W3[(k0 + 1) * 16 + e]);
        }
    for (int q = 0; q < 4; ++q)
        for (int r = 0; r < 4; ++r)
            img[(14 + q) * 256 + l * 4 + r] = __float_as_uint(b2[16 * q + 4 * g + r]);
    for (int r = 0; r < 4; ++r)
        img[18 * 256 + l * 4 + r] = __float_as_uint(b3[4 * g + r]);
}

// ---------------- RK4 edge MLP: MFMA + permlane, zero LDS ----------------
// __launch_bounds__(256, 4): 4 waves/EU -> VGPR cap 128, enough to keep ALL
// weight fragments (84 VGPRs persistent) resident. Plain (256) capped VGPR at
// 64 -> compiler rematerialized fragments from global every rhs (r2/r3 killer).
__global__ __launch_bounds__(256, 4) void rk4_kernel(
    const int* __restrict__ ei, const float* __restrict__ ea,
    const float* __restrict__ xg, const uint32_t* __restrict__ img,
    float* __restrict__ out) {
    const int tid = threadIdx.x;
    const int w = tid >> 6, l = tid & 63;
    const int e = l & 15, g = l >> 4;
    const int edge = blockIdx.x * 64 + w * 16 + e;

    // persistent weight fragments (must stay register-resident)
    bf16x8 W1f[4], W2f[2][4], W3f[2];
    f32x4 b2f[4], b3f;
    {
        union { uint4 a; bf16x8 b; f32x4 f; } t;
#pragma unroll
        for (int q = 0; q < 4; ++q) { t.a = *(const uint4*)(img + q * 256 + l * 4); W1f[q] = t.b; }
#pragma unroll
        for (int tt = 0; tt < 2; ++tt)
#pragma unroll
            for (int q = 0; q < 4; ++q) {
                t.a = *(const uint4*)(img + (4 + tt * 4 + q) * 256 + l * 4);
                W2f[tt][q] = t.b;
            }
#pragma unroll
        for (int tt = 0; tt < 2; ++tt) { t.a = *(const uint4*)(img + (12 + tt) * 256 + l * 4); W3f[tt] = t.b; }
#pragma unroll
        for (int q = 0; q < 4; ++q) { t.a = *(const uint4*)(img + (14 + q) * 256 + l * 4); b2f[q] = t.f; }
        t.a = *(const uint4*)(img + 18 * 256 + l * 4); b3f = t.f;
    }

    // static rows of layer-1 B operand: g0 = f = [src4|tgt4], g3 = bias-one at k=24
    uint32_t St0 = 0u, St1 = 0u, St2 = 0u, St3 = 0u;
    if (g == 0) {
        int r = ei[edge], c = ei[NE + edge];
        float4 sv = *(const float4*)(xg + (size_t)r * 4);
        float4 tv = *(const float4*)(xg + (size_t)c * 4);
        St0 = cvtpk(sv.x, sv.y); St1 = cvtpk(sv.z, sv.w);
        St2 = cvtpk(tv.x, tv.y); St3 = cvtpk(tv.z, tv.w);
    } else if (g == 3) {
        St0 = 0x00003F80u;  // bf16(1.0) at k=24
    }
    const bool mid = (g == 1) || (g == 2);

    float4 y4 = *(const float4*)(ea + (size_t)edge * 16 + 4 * g);
    float yv0 = y4.x, yv1 = y4.y, yv2 = y4.z, yv3 = y4.w;

    const f32x4 zero4 = {0.f, 0.f, 0.f, 0.f};
    const float dt6 = 0.125f / 6.0f;

    auto rhs = [&](float a0, float a1, float a2, float a3) -> f32x4 {
        // layer-1 B: rows g1/g2 from arg via permlane, g0/g3 static
        uint32_t aP = cvtpk(a0, a1), bP = cvtpk(a2, a3);
        uint32_t A1 = aP, A2 = aP; pl16(A1, A2);
        uint32_t C1 = bP, C2 = bP; pl16(C1, C2);
        uint4 bb;
        bb.x = mid ? A1 : St0;
        bb.y = mid ? C1 : St1;
        bb.z = mid ? A2 : St2;
        bb.w = mid ? C2 : St3;
        bf16x8 B1 = as_bf(bb);
        // layer 1 (K=32, bias folded at k=24)
        f32x4 h0 = MFMA16(W1f[0], B1, zero4);
        f32x4 h1 = MFMA16(W1f[1], B1, zero4);
        f32x4 h2 = MFMA16(W1f[2], B1, zero4);
        f32x4 h3 = MFMA16(W1f[3], B1, zero4);
        // relu + pack + transpose -> B20/B21
        uint32_t x0 = cvtpk(fmaxf(h0[0], 0.f), fmaxf(h0[1], 0.f));
        uint32_t x1 = cvtpk(fmaxf(h0[2], 0.f), fmaxf(h0[3], 0.f));
        uint32_t u0 = cvtpk(fmaxf(h1[0], 0.f), fmaxf(h1[1], 0.f));
        uint32_t u1 = cvtpk(fmaxf(h1[2], 0.f), fmaxf(h1[3], 0.f));
        uint32_t z0 = cvtpk(fmaxf(h2[0], 0.f), fmaxf(h2[1], 0.f));
        uint32_t z1 = cvtpk(fmaxf(h2[2], 0.f), fmaxf(h2[3], 0.f));
        uint32_t v0 = cvtpk(fmaxf(h3[0], 0.f), fmaxf(h3[1], 0.f));
        uint32_t v1 = cvtpk(fmaxf(h3[2], 0.f), fmaxf(h3[3], 0.f));
        pl32(x0, u0); pl16(x0, u0);
        pl32(x1, u1); pl16(x1, u1);
        pl32(z0, v0); pl16(z0, v0);
        pl32(z1, v1); pl16(z1, v1);
        uint4 q20; q20.x = x0; q20.y = x1; q20.z = u0; q20.w = u1;
        uint4 q21; q21.x = z0; q21.y = z1; q21.z = v0; q21.w = v1;
        bf16x8 B20 = as_bf(q20), B21 = as_bf(q21);
        // layer 2 (K=64, bias via C-in)
        f32x4 p0 = MFMA16(W2f[0][0], B20, b2f[0]); p0 = MFMA16(W2f[1][0], B21, p0);
        f32x4 p1 = MFMA16(W2f[0][1], B20, b2f[1]); p1 = MFMA16(W2f[1][1], B21, p1);
        f32x4 p2 = MFMA16(W2f[0][2], B20, b2f[2]); p2 = MFMA16(W2f[1][2], B21, p2);
        f32x4 p3 = MFMA16(W2f[0][3], B20, b2f[3]); p3 = MFMA16(W2f[1][3], B21, p3);
        // relu + pack + transpose -> B30/B31
        uint32_t m0 = cvtpk(fmaxf(p0[0], 0.f), fmaxf(p0[1], 0.f));
        uint32_t m1 = cvtpk(fmaxf(p0[2], 0.f), fmaxf(p0[3], 0.f));
        uint32_t n0 = cvtpk(fmaxf(p1[0], 0.f), fmaxf(p1[1], 0.f));
        uint32_t n1 = cvtpk(fmaxf(p1[2], 0.f), fmaxf(p1[3], 0.f));
        uint32_t o0 = cvtpk(fmaxf(p2[0], 0.f), fmaxf(p2[1], 0.f));
        uint32_t o1 = cvtpk(fmaxf(p2[2], 0.f), fmaxf(p2[3], 0.f));
        uint32_t r0 = cvtpk(fmaxf(p3[0], 0.f), fmaxf(p3[1], 0.f));
        uint32_t r1 = cvtpk(fmaxf(p3[2], 0.f), fmaxf(p3[3], 0.f));
        pl32(m0, n0); pl16(m0, n0);
        pl32(m1, n1); pl16(m1, n1);
        pl32(o0, r0); pl16(o0, r0);
        pl32(o1, r1); pl16(o1, r1);
        uint4 q30; q30.x = m0; q30.y = m1; q30.z = n0; q30.w = n1;
        uint4 q31; q31.x = o0; q31.y = o1; q31.z = r0; q31.w = r1;
        bf16x8 B30 = as_bf(q30), B31 = as_bf(q31);
        // layer 3 (K=64, M=16)
        f32x4 kk = MFMA16(W3f[0], B30, b3f);
        kk = MFMA16(W3f[1], B31, kk);
        return kk;
    };

#pragma unroll 1
    for (int step = 0; step < 8; ++step) {
        float a0 = yv0, a1 = yv1, a2 = yv2, a3 = yv3;
        float c0 = 0.f, c1 = 0.f, c2 = 0.f, c3 = 0.f;
#pragma unroll 1
        for (int s = 0; s < 4; ++s) {
            f32x4 kk = rhs(a0, a1, a2, a3);
            float wk = (s == 1 || s == 2) ? 2.f : 1.f;
            float cs = (s < 2) ? 0.0625f : (s == 2) ? 0.125f : 0.f;
            c0 = fmaf(wk, kk[0], c0); c1 = fmaf(wk, kk[1], c1);
            c2 = fmaf(wk, kk[2], c2); c3 = fmaf(wk, kk[3], c3);
            a0 = fmaf(cs, kk[0], yv0); a1 = fmaf(cs, kk[1], yv1);
            a2 = fmaf(cs, kk[2], yv2); a3 = fmaf(cs, kk[3], yv3);
        }
        yv0 = fmaf(dt6, c0, yv0); yv1 = fmaf(dt6, c1, yv1);
        yv2 = fmaf(dt6, c2, yv2); yv3 = fmaf(dt6, c3, yv3);
    }

    *(float4*)(out + (size_t)edge * 16 + 4 * g) = make_float4(yv0, yv1, yv2, yv3);
}

extern "C" void kernel_launch(void* const* d_in, const int* in_sizes, int n_in,
                              void* d_out, int out_size, void* d_ws, size_t ws_size,
                              hipStream_t stream) {
    const float* x     = (const float*)d_in[0];
    const int*   ei    = (const int*)d_in[1];
    const float* ea    = (const float*)d_in[2];
    const float* Wg    = (const float*)d_in[3];
    const float* a_src = (const float*)d_in[4];
    const float* a_dst = (const float*)d_in[5];
    const float* b_gat = (const float*)d_in[6];
    const float* W1    = (const float*)d_in[7];
    const float* b1    = (const float*)d_in[8];
    const float* W2    = (const float*)d_in[9];
    const float* b2    = (const float*)d_in[10];
    const float* W3    = (const float*)d_in[11];
    const float* b3    = (const float*)d_in[12];

    float* ws  = (float*)d_ws;
    float* h   = ws + OFF_H;
    float* hs  = ws + OFF_HS;
    float* hd  = ws + OFF_HD;
    float* den = ws + OFF_DEN;
    float* xg  = ws + OFF_XG;
    float* p   = ws + OFF_P;
    uint32_t* img = (uint32_t*)(ws + OFF_IMG);

    prep_kernel<<<1, 64, 0, stream>>>(W1, b1, W2, b2, W3, b3, img);
    node_kernel<<<(NN + 255) / 256, 256, 0, stream>>>(x, Wg, a_src, a_dst, b_gat,
                                                      h, hs, hd, den, xg);
    int ne_tot = NE + NN;
    att_kernel<<<(ne_tot + 255) / 256, 256, 0, stream>>>(ei, hs, hd, p, den);
    agg_kernel<<<(ne_tot + 255) / 256, 256, 0, stream>>>(ei, h, p, den, xg);
    rk4_kernel<<<NE / 64, 256, 0, stream>>>(ei, ea, xg, img, (float*)d_out);
}